// Round 7
// baseline (29.587 us; speedup 1.0000x reference)
//
#include <hip/hip_runtime.h>
#include <math.h>

typedef float f32x2 __attribute__((ext_vector_type(2)));
typedef unsigned long long u64;

#define L_RES 512
#define N_BATCH 64
#define NTHR 256
#define BLK_PER_B 8                       // blocks per batch
#define NBLOCKS (N_BATCH * BLK_PER_B)     // 512 blocks = 2 per CU (co-resident)
#define R_ROWS 8                          // rows held in registers per thread
#define JSTRIDE (BLK_PER_B * (NTHR/64))   // 32 wave-phases per batch -> 16 j-iters
#define EPOCH_MAGIC 0x52474E4Cu           // "RGNL" tag, != 0xAAAAAAAA poison, != 0

// Identity: 2 * sum_{i<j} (din-dtg)^2  ==  sum over ALL ordered (i,j) of
//   [ sq_in + sq_tg - 2*sqrt(sq_in*sq_tg) ]   (diagonal contributes 0).
//
// Completion protocol (self-contained per call; tolerates ANY initial d_ws
// state -- poison 0xAA.., zeros, or leftover 0):
//   cnt (u64) = [epoch tag | arrival count].
//   1. block 0 / thread 0 stores (MAGIC<<32 | 0) with release at kernel start.
//   2. each block computes + stores its partial, then spins (acquire) until
//      hi32 == MAGIC (in practice already set: block 0 tags before ~3us of
//      compute), then fetch_add(1) with acq_rel.
//   3. all increments happen after the tag store, so lo32 values are exactly
//      0..511 for THIS call; the block seeing 511 is the true last arrival.
//      It reads all 512 partials (visible via the release-RMW chain),
//      finalizes in fixed order (bit-deterministic), writes out, and clears
//      cnt to 0.
//   Co-residency of all 512 blocks (spin safety): __launch_bounds__(256,2)
//   => 2 blocks/CU; LDS 12.3KB*2 and VGPR<<256 both fit.

__global__ __launch_bounds__(NTHR, 2) void rgn_fused_kernel(
    const float* __restrict__ inp, const float* __restrict__ tgt,
    float* __restrict__ part,      // [NBLOCKS]
    u64* __restrict__ cnt,         // epoch-tagged arrival counter
    float* __restrict__ out)
{
    __shared__ f32x2 sx[L_RES];     // (input.x, target.x) per residue
    __shared__ f32x2 sy[L_RES];
    __shared__ f32x2 sz[L_RES];
    __shared__ float wsum[NTHR / 64];
    __shared__ int s_fin;

    const int blk  = blockIdx.x;
    const int b    = blk >> 3;        // batch id
    const int q    = blk & 7;         // block-within-batch
    const int t    = threadIdx.x;
    const int lane = t & 63;
    const int wv   = t >> 6;

    // open this call's epoch before doing any work
    if (blk == 0 && t == 0) {
        __hip_atomic_store(cnt, (u64)EPOCH_MAGIC << 32, __ATOMIC_RELEASE,
                           __HIP_MEMORY_SCOPE_AGENT);
    }

    const float* __restrict__ binp = inp + (size_t)b * L_RES * 9;
    const float* __restrict__ btgt = tgt + (size_t)b * L_RES * 9;

    // stage CA atom (atom 1 -> floats 3..5 of each residue's 9)
    for (int l = t; l < L_RES; l += NTHR) {
        sx[l] = (f32x2){binp[l*9+3], btgt[l*9+3]};
        sy[l] = (f32x2){binp[l*9+4], btgt[l*9+4]};
        sz[l] = (f32x2){binp[l*9+5], btgt[l*9+5]};
    }
    __syncthreads();

    // 8 rows per thread, strided by 64: i = lane + 64*r
    f32x2 rx[R_ROWS], ry[R_ROWS], rz[R_ROWS];
    #pragma unroll
    for (int r = 0; r < R_ROWS; ++r) {
        const int i = lane + 64 * r;
        rx[r] = sx[i]; ry[r] = sy[i]; rz[r] = sz[i];
    }

    f32x2 asq = (f32x2){0.0f, 0.0f};   // sum of (sq_in, sq_tg)
    float acx = 0.0f;                   // sum of sqrt(sq_in*sq_tg)

    const int ph = q * (NTHR / 64) + wv;           // 0..31
    for (int j = ph; j < L_RES; j += JSTRIDE) {    // 16 iterations
        const f32x2 jx = sx[j], jy = sy[j], jz = sz[j];  // wave-uniform broadcast
        #pragma unroll
        for (int r = 0; r < R_ROWS; ++r) {
            f32x2 dx = rx[r] - jx;
            f32x2 dy = ry[r] - jy;
            f32x2 dz = rz[r] - jz;
            f32x2 sq = __builtin_elementwise_fma(dz, dz,
                        __builtin_elementwise_fma(dy, dy, dx * dx));
            asq += sq;
            acx += __builtin_amdgcn_sqrtf(sq.x * sq.y);
        }
    }

    // per-thread combine, then block reduce
    float a = (asq.x + asq.y) - 2.0f * acx;
    for (int o = 32; o > 0; o >>= 1) a += __shfl_down(a, o);
    if (lane == 0) wsum[wv] = a;
    __syncthreads();

    if (t == 0) {
        float s = wsum[0] + wsum[1] + wsum[2] + wsum[3];
        __hip_atomic_store(&part[blk], s, __ATOMIC_RELAXED, __HIP_MEMORY_SCOPE_AGENT);
        // wait for this call's epoch tag (normally already visible)
        u64 v;
        do {
            v = __hip_atomic_load(cnt, __ATOMIC_ACQUIRE, __HIP_MEMORY_SCOPE_AGENT);
            if ((unsigned)(v >> 32) == EPOCH_MAGIC) break;
            __builtin_amdgcn_s_sleep(8);
        } while (true);
        u64 old = __hip_atomic_fetch_add(cnt, 1ull, __ATOMIC_ACQ_REL,
                                         __HIP_MEMORY_SCOPE_AGENT);
        s_fin = ((unsigned)(old & 0xFFFFFFFFull) == NBLOCKS - 1);
    }
    __syncthreads();

    // the true last-arriving block of THIS call finalizes (one wave)
    if (s_fin) {
        if (t < 64) {
            // lane t = batch t: ordered sum of its 8 partials
            const float4* pp = (const float4*)&part[t * BLK_PER_B];
            float4 p0 = pp[0], p1 = pp[1];
            float ss = ((((((p0.x + p0.y) + p0.z) + p0.w) + p1.x) + p1.y) + p1.z) + p1.w;
            // ss = 2 * sum_{i<j} (din-dtg)^2 for batch t
            float r = sqrtf(ss + 1e-6f) * (1.0f / (sqrtf(512.0f * 511.0f) * 512.0f));
            for (int o = 32; o > 0; o >>= 1) r += __shfl_down(r, o);
            if (t == 0) out[0] = r * (1.0f / (float)N_BATCH);
        }
        __syncthreads();
        if (t == 0) {
            // close the epoch: leftover state (0) is inert for the next call
            __hip_atomic_store(cnt, 0ull, __ATOMIC_RELEASE, __HIP_MEMORY_SCOPE_AGENT);
        }
    }
}

extern "C" void kernel_launch(void* const* d_in, const int* in_sizes, int n_in,
                              void* d_out, int out_size, void* d_ws, size_t ws_size,
                              hipStream_t stream) {
    const float* inp = (const float*)d_in[0];   // [N,3,3] f32
    const float* tgt = (const float*)d_in[1];   // [N,3,3] f32
    char* ws = (char*)d_ws;
    float* part = (float*)(ws);                 // 512 floats @ 0
    u64*   cnt  = (u64*)(ws + 4096);            // epoch-tagged counter, own line
    float* out  = (float*)d_out;

    rgn_fused_kernel<<<NBLOCKS, NTHR, 0, stream>>>(inp, tgt, part, cnt, out);
}

// Round 8
// 19.781 us; speedup vs baseline: 1.4957x; 1.4957x over previous
//
#include <hip/hip_runtime.h>
#include <math.h>

typedef float f32x2 __attribute__((ext_vector_type(2)));

#define L_RES 512
#define N_BATCH 64
#define NTHR 256
#define BLK_PER_B 8                       // blocks per batch
#define NBLOCKS (N_BATCH * BLK_PER_B)     // 512 blocks = 2 per CU
#define R_ROWS 8                          // rows held in registers per thread
#define JSTRIDE (BLK_PER_B * (NTHR/64))   // 32 wave-phases per batch -> 16 j-iters
#define FLAG_PAT 0xCCCCCCCCu              // != 0xAAAAAAAA poison, != 0
#define FLAG_STRIDE 16                    // u32s -> 64 B between flags

// Identity: 2 * sum_{i<j} (din-dtg)^2  ==  sum over ALL ordered (i,j) of
//   [ sq_in + sq_tg - 2*sqrt(sq_in*sq_tg) ]   (diagonal contributes 0).
//
// Completion protocol (no RMWs, no shared hot line, any-initial-state sound):
//   - each block: store partial (relaxed), then set its own flag word
//     (release) at a 64B-strided private address. 512 independent stores.
//   - block 0, wave 0: poll flags (lane t: acquire-loads flags of blocks
//     t*8..t*8+7 -- exactly the blocks whose partials lane t will read) until
//     __all set; finalize in fixed order; write out; clear flags (relaxed --
//     visible to the next stream-ordered call via kernel completion).
//   - poison 0xAAAAAAAA / cleared 0 both != FLAG_PAT, so the pattern appears
//     only via THIS call's 512 stores. Writers never wait -> deadlock-free.

__global__ __launch_bounds__(NTHR) void rgn_fused_kernel(
    const float* __restrict__ inp, const float* __restrict__ tgt,
    float* __restrict__ part,      // [NBLOCKS]
    unsigned* __restrict__ flags,  // [NBLOCKS * FLAG_STRIDE]
    float* __restrict__ out)
{
    __shared__ f32x2 sx[L_RES];     // (input.x, target.x) per residue
    __shared__ f32x2 sy[L_RES];
    __shared__ f32x2 sz[L_RES];
    __shared__ float wsum[NTHR / 64];

    const int blk  = blockIdx.x;
    const int b    = blk >> 3;        // batch id
    const int q    = blk & 7;         // block-within-batch
    const int t    = threadIdx.x;
    const int lane = t & 63;
    const int wv   = t >> 6;

    const float* __restrict__ binp = inp + (size_t)b * L_RES * 9;
    const float* __restrict__ btgt = tgt + (size_t)b * L_RES * 9;

    // stage CA atom (atom 1 -> floats 3..5 of each residue's 9)
    for (int l = t; l < L_RES; l += NTHR) {
        sx[l] = (f32x2){binp[l*9+3], btgt[l*9+3]};
        sy[l] = (f32x2){binp[l*9+4], btgt[l*9+4]};
        sz[l] = (f32x2){binp[l*9+5], btgt[l*9+5]};
    }
    __syncthreads();

    // 8 rows per thread, strided by 64: i = lane + 64*r
    f32x2 rx[R_ROWS], ry[R_ROWS], rz[R_ROWS];
    #pragma unroll
    for (int r = 0; r < R_ROWS; ++r) {
        const int i = lane + 64 * r;
        rx[r] = sx[i]; ry[r] = sy[i]; rz[r] = sz[i];
    }

    f32x2 asq = (f32x2){0.0f, 0.0f};   // sum of (sq_in, sq_tg)
    float acx = 0.0f;                   // sum of sqrt(sq_in*sq_tg)

    const int ph = q * (NTHR / 64) + wv;           // 0..31
    for (int j = ph; j < L_RES; j += JSTRIDE) {    // 16 iterations
        const f32x2 jx = sx[j], jy = sy[j], jz = sz[j];  // wave-uniform broadcast
        #pragma unroll
        for (int r = 0; r < R_ROWS; ++r) {
            f32x2 dx = rx[r] - jx;
            f32x2 dy = ry[r] - jy;
            f32x2 dz = rz[r] - jz;
            f32x2 sq = __builtin_elementwise_fma(dz, dz,
                        __builtin_elementwise_fma(dy, dy, dx * dx));
            asq += sq;
            acx += __builtin_amdgcn_sqrtf(sq.x * sq.y);
        }
    }

    // per-thread combine, then block reduce
    float a = (asq.x + asq.y) - 2.0f * acx;
    for (int o = 32; o > 0; o >>= 1) a += __shfl_down(a, o);
    if (lane == 0) wsum[wv] = a;
    __syncthreads();

    if (t == 0) {
        float s = wsum[0] + wsum[1] + wsum[2] + wsum[3];
        __hip_atomic_store(&part[blk], s, __ATOMIC_RELAXED, __HIP_MEMORY_SCOPE_AGENT);
        // publish: release orders the partial store before the flag store
        __hip_atomic_store(&flags[blk * FLAG_STRIDE], FLAG_PAT, __ATOMIC_RELEASE,
                           __HIP_MEMORY_SCOPE_AGENT);
    }

    // block 0, wave 0: sole finalizer
    if (blk == 0 && t < 64) {
        // poll: lane t watches the 8 blocks whose partials it will read
        for (;;) {
            bool ready = true;
            #pragma unroll
            for (int k = 0; k < 8; ++k) {
                unsigned f = __hip_atomic_load(&flags[(t * 8 + k) * FLAG_STRIDE],
                                               __ATOMIC_ACQUIRE,
                                               __HIP_MEMORY_SCOPE_AGENT);
                ready &= (f == FLAG_PAT);
            }
            if (__all(ready)) break;
            __builtin_amdgcn_s_sleep(2);
        }
        // lane t = batch t: ordered sum of its 8 partials
        const float4* pp = (const float4*)&part[t * BLK_PER_B];
        float4 p0 = pp[0], p1 = pp[1];
        float ss = ((((((p0.x + p0.y) + p0.z) + p0.w) + p1.x) + p1.y) + p1.z) + p1.w;
        // ss = 2 * sum_{i<j} (din-dtg)^2 for batch t
        float r = sqrtf(ss + 1e-6f) * (1.0f / (sqrtf(512.0f * 511.0f) * 512.0f));
        for (int o = 32; o > 0; o >>= 1) r += __shfl_down(r, o);
        if (t == 0) out[0] = r * (1.0f / (float)N_BATCH);
        // clear flags for the next stream-ordered call (kernel completion
        // guarantees visibility; intra-call ordering vs the loads above is
        // irrelevant -- different addresses, same call)
        #pragma unroll
        for (int k = 0; k < 8; ++k)
            __hip_atomic_store(&flags[(t * 8 + k) * FLAG_STRIDE], 0u,
                               __ATOMIC_RELAXED, __HIP_MEMORY_SCOPE_AGENT);
    }
}

extern "C" void kernel_launch(void* const* d_in, const int* in_sizes, int n_in,
                              void* d_out, int out_size, void* d_ws, size_t ws_size,
                              hipStream_t stream) {
    const float* inp = (const float*)d_in[0];   // [N,3,3] f32
    const float* tgt = (const float*)d_in[1];   // [N,3,3] f32
    char* ws = (char*)d_ws;
    float*    part  = (float*)(ws);             // 512 floats @ 0
    unsigned* flags = (unsigned*)(ws + 4096);   // 512 x 64B-strided flag words
    float*    out   = (float*)d_out;

    rgn_fused_kernel<<<NBLOCKS, NTHR, 0, stream>>>(inp, tgt, part, flags, out);
}

// Round 9
// 18.751 us; speedup vs baseline: 1.5779x; 1.0549x over previous
//
#include <hip/hip_runtime.h>
#include <math.h>

typedef float f32x2 __attribute__((ext_vector_type(2)));

#define L_RES 512
#define N_BATCH 64
#define NTHR 256
#define BLK_PER_B 8                       // blocks per batch
#define NBLOCKS (N_BATCH * BLK_PER_B)     // 512 blocks = 2 per CU
#define R_ROWS 8                          // rows held in registers per thread
#define JSTRIDE (BLK_PER_B * (NTHR/64))   // 32 wave-phases per batch -> 16 j-iters
#define FLAG_PAT 0xCCCCCCCCu              // != 0xAAAAAAAA poison, != 0
#define FLAG_STRIDE 16                    // u32s -> 64 B between flags

// Identity: 2 * sum_{i<j} (din-dtg)^2  ==  sum over ALL ordered (i,j) of
//   [ sq_in + sq_tg - 2*sqrt(sq_in*sq_tg) ]   (diagonal contributes 0).
//
// XCD-aware decode (this round's change): hardware assigns XCD = blockIdx % 8.
// Decoding b = blockIdx % 64, q = blockIdx / 64 puts all 8 blocks of a batch
// on the SAME XCD (same blockIdx mod 8) -> each batch's coordinates occupy
// exactly one XCD L2 (R6 profile showed 4x over-fetch with the naive decode),
// 64 blocks/XCD balanced. Staging becomes L2-hit for 7 of 8 blocks.
//
// Completion protocol (unchanged from R7, any-initial-state sound): per-block
// private flag words (release) at 64B-strided addresses; block with
// blockIdx==0 finalizes after polling all 512 flags (acquire); fixed-order
// sums -> bit-deterministic; flags cleared for the next stream-ordered call.

__global__ __launch_bounds__(NTHR) void rgn_fused_kernel(
    const float* __restrict__ inp, const float* __restrict__ tgt,
    float* __restrict__ part,      // [NBLOCKS] indexed by logical id b*8+q
    unsigned* __restrict__ flags,  // [NBLOCKS * FLAG_STRIDE], logical id
    float* __restrict__ out)
{
    __shared__ f32x2 sx[L_RES];     // (input.x, target.x) per residue
    __shared__ f32x2 sy[L_RES];
    __shared__ f32x2 sz[L_RES];
    __shared__ float wsum[NTHR / 64];

    const int bhw  = blockIdx.x;
    const int b    = bhw & 63;        // batch id   (same XCD for all q)
    const int q    = bhw >> 6;        // block-within-batch 0..7
    const int lid  = b * BLK_PER_B + q;  // logical block id for part/flags
    const int t    = threadIdx.x;
    const int lane = t & 63;
    const int wv   = t >> 6;

    const float* __restrict__ binp = inp + (size_t)b * L_RES * 9;
    const float* __restrict__ btgt = tgt + (size_t)b * L_RES * 9;

    // stage CA atom (atom 1 -> floats 3..5 of each residue's 9)
    for (int l = t; l < L_RES; l += NTHR) {
        sx[l] = (f32x2){binp[l*9+3], btgt[l*9+3]};
        sy[l] = (f32x2){binp[l*9+4], btgt[l*9+4]};
        sz[l] = (f32x2){binp[l*9+5], btgt[l*9+5]};
    }
    __syncthreads();

    // 8 rows per thread, strided by 64: i = lane + 64*r
    f32x2 rx[R_ROWS], ry[R_ROWS], rz[R_ROWS];
    #pragma unroll
    for (int r = 0; r < R_ROWS; ++r) {
        const int i = lane + 64 * r;
        rx[r] = sx[i]; ry[r] = sy[i]; rz[r] = sz[i];
    }

    f32x2 asq = (f32x2){0.0f, 0.0f};   // sum of (sq_in, sq_tg)
    float acx = 0.0f;                   // sum of sqrt(sq_in*sq_tg)

    const int ph = q * (NTHR / 64) + wv;           // 0..31
    for (int j = ph; j < L_RES; j += JSTRIDE) {    // 16 iterations
        const f32x2 jx = sx[j], jy = sy[j], jz = sz[j];  // wave-uniform broadcast
        #pragma unroll
        for (int r = 0; r < R_ROWS; ++r) {
            f32x2 dx = rx[r] - jx;
            f32x2 dy = ry[r] - jy;
            f32x2 dz = rz[r] - jz;
            f32x2 sq = __builtin_elementwise_fma(dz, dz,
                        __builtin_elementwise_fma(dy, dy, dx * dx));
            asq += sq;
            acx += __builtin_amdgcn_sqrtf(sq.x * sq.y);
        }
    }

    // per-thread combine, then block reduce
    float a = (asq.x + asq.y) - 2.0f * acx;
    for (int o = 32; o > 0; o >>= 1) a += __shfl_down(a, o);
    if (lane == 0) wsum[wv] = a;
    __syncthreads();

    if (t == 0) {
        float s = wsum[0] + wsum[1] + wsum[2] + wsum[3];
        __hip_atomic_store(&part[lid], s, __ATOMIC_RELAXED, __HIP_MEMORY_SCOPE_AGENT);
        // publish: release orders the partial store before the flag store
        __hip_atomic_store(&flags[lid * FLAG_STRIDE], FLAG_PAT, __ATOMIC_RELEASE,
                           __HIP_MEMORY_SCOPE_AGENT);
    }

    // hw block 0 (logical 0), wave 0: sole finalizer
    if (bhw == 0 && t < 64) {
        // poll: lane t watches the 8 blocks whose partials it will read
        for (;;) {
            bool ready = true;
            #pragma unroll
            for (int k = 0; k < 8; ++k) {
                unsigned f = __hip_atomic_load(&flags[(t * 8 + k) * FLAG_STRIDE],
                                               __ATOMIC_ACQUIRE,
                                               __HIP_MEMORY_SCOPE_AGENT);
                ready &= (f == FLAG_PAT);
            }
            if (__all(ready)) break;
            __builtin_amdgcn_s_sleep(2);
        }
        // lane t = batch t: ordered sum of its 8 partials
        const float4* pp = (const float4*)&part[t * BLK_PER_B];
        float4 p0 = pp[0], p1 = pp[1];
        float ss = ((((((p0.x + p0.y) + p0.z) + p0.w) + p1.x) + p1.y) + p1.z) + p1.w;
        // ss = 2 * sum_{i<j} (din-dtg)^2 for batch t
        float r = sqrtf(ss + 1e-6f) * (1.0f / (sqrtf(512.0f * 511.0f) * 512.0f));
        for (int o = 32; o > 0; o >>= 1) r += __shfl_down(r, o);
        if (t == 0) out[0] = r * (1.0f / (float)N_BATCH);
        // clear flags for the next stream-ordered call
        #pragma unroll
        for (int k = 0; k < 8; ++k)
            __hip_atomic_store(&flags[(t * 8 + k) * FLAG_STRIDE], 0u,
                               __ATOMIC_RELAXED, __HIP_MEMORY_SCOPE_AGENT);
    }
}

extern "C" void kernel_launch(void* const* d_in, const int* in_sizes, int n_in,
                              void* d_out, int out_size, void* d_ws, size_t ws_size,
                              hipStream_t stream) {
    const float* inp = (const float*)d_in[0];   // [N,3,3] f32
    const float* tgt = (const float*)d_in[1];   // [N,3,3] f32
    char* ws = (char*)d_ws;
    float*    part  = (float*)(ws);             // 512 floats @ 0
    unsigned* flags = (unsigned*)(ws + 4096);   // 512 x 64B-strided flag words
    float*    out   = (float*)d_out;

    rgn_fused_kernel<<<NBLOCKS, NTHR, 0, stream>>>(inp, tgt, part, flags, out);
}

// Round 10
// 17.646 us; speedup vs baseline: 1.6767x; 1.0626x over previous
//
#include <hip/hip_runtime.h>
#include <math.h>

typedef float f32x2 __attribute__((ext_vector_type(2)));
typedef unsigned long long u64;

#define L_RES 512
#define N_BATCH 64
#define NTHR 256
#define BLK_PER_B 8                       // blocks per batch
#define NBLOCKS (N_BATCH * BLK_PER_B)     // 512 blocks = 2 per CU
#define R_ROWS 8                          // rows held in registers per thread
#define JSTRIDE (BLK_PER_B * (NTHR/64))   // 32 wave-phases per batch -> 16 j-iters
#define FLAG_PAT 0xCCCCCCCCu              // != 0xAAAAAAAA poison, != 0
#define TAG_STRIDE 8                      // u64s -> 64 B between tagged words

// Identity: 2 * sum_{i<j} (din-dtg)^2  ==  sum over ALL ordered (i,j) of
//   [ sq_in + sq_tg - 2*sqrt(sq_in*sq_tg) ]   (diagonal contributes 0).
//
// Tagged-payload completion (this round's change): each block publishes ONE
// 8-byte word  (FLAG_PAT<<32) | f32_bits(partial)  with a release store at a
// 64B-strided private address. The finalizer's poll reads readiness AND the
// payload in a single acquire load -- no separate part[] array, no second
// round-trip, no payload/flag ordering concern (payload rides inside the
// synchronizing word). Poison hi32 (0xAAAAAAAA) and cleared hi32 (0) both
// != FLAG_PAT -> pattern appears only via THIS call's stores; sound for any
// initial d_ws state. Writers never wait -> deadlock-free at any occupancy.
//
// XCD-aware decode (kept from R8): b = blockIdx & 63, q = blockIdx >> 6 puts
// all 8 blocks of a batch on the same XCD (XCD = blockIdx % 8) -> one L2 copy
// per batch's coordinates, 64 blocks/XCD balanced.

__global__ __launch_bounds__(NTHR) void rgn_fused_kernel(
    const float* __restrict__ inp, const float* __restrict__ tgt,
    u64* __restrict__ tagged,      // [NBLOCKS * TAG_STRIDE], logical id b*8+q
    float* __restrict__ out)
{
    __shared__ f32x2 sx[L_RES];     // (input.x, target.x) per residue
    __shared__ f32x2 sy[L_RES];
    __shared__ f32x2 sz[L_RES];
    __shared__ float wsum[NTHR / 64];

    const int bhw  = blockIdx.x;
    const int b    = bhw & 63;        // batch id   (same XCD for all q)
    const int q    = bhw >> 6;        // block-within-batch 0..7
    const int lid  = b * BLK_PER_B + q;  // logical block id
    const int t    = threadIdx.x;
    const int lane = t & 63;
    const int wv   = t >> 6;

    const float* __restrict__ binp = inp + (size_t)b * L_RES * 9;
    const float* __restrict__ btgt = tgt + (size_t)b * L_RES * 9;

    // stage CA atom (atom 1 -> floats 3..5 of each residue's 9)
    for (int l = t; l < L_RES; l += NTHR) {
        sx[l] = (f32x2){binp[l*9+3], btgt[l*9+3]};
        sy[l] = (f32x2){binp[l*9+4], btgt[l*9+4]};
        sz[l] = (f32x2){binp[l*9+5], btgt[l*9+5]};
    }
    __syncthreads();

    // 8 rows per thread, strided by 64: i = lane + 64*r
    f32x2 rx[R_ROWS], ry[R_ROWS], rz[R_ROWS];
    #pragma unroll
    for (int r = 0; r < R_ROWS; ++r) {
        const int i = lane + 64 * r;
        rx[r] = sx[i]; ry[r] = sy[i]; rz[r] = sz[i];
    }

    f32x2 asq = (f32x2){0.0f, 0.0f};   // sum of (sq_in, sq_tg)
    float acx = 0.0f;                   // sum of sqrt(sq_in*sq_tg)

    const int ph = q * (NTHR / 64) + wv;           // 0..31
    for (int j = ph; j < L_RES; j += JSTRIDE) {    // 16 iterations
        const f32x2 jx = sx[j], jy = sy[j], jz = sz[j];  // wave-uniform broadcast
        #pragma unroll
        for (int r = 0; r < R_ROWS; ++r) {
            f32x2 dx = rx[r] - jx;
            f32x2 dy = ry[r] - jy;
            f32x2 dz = rz[r] - jz;
            f32x2 sq = __builtin_elementwise_fma(dz, dz,
                        __builtin_elementwise_fma(dy, dy, dx * dx));
            asq += sq;
            acx += __builtin_amdgcn_sqrtf(sq.x * sq.y);
        }
    }

    // per-thread combine, then block reduce
    float a = (asq.x + asq.y) - 2.0f * acx;
    for (int o = 32; o > 0; o >>= 1) a += __shfl_down(a, o);
    if (lane == 0) wsum[wv] = a;
    __syncthreads();

    if (t == 0) {
        float s = wsum[0] + wsum[1] + wsum[2] + wsum[3];
        u64 v = ((u64)FLAG_PAT << 32) | (u64)__float_as_uint(s);
        __hip_atomic_store(&tagged[lid * TAG_STRIDE], v, __ATOMIC_RELEASE,
                           __HIP_MEMORY_SCOPE_AGENT);
    }

    // hw block 0 (logical 0), wave 0: sole finalizer
    if (bhw == 0 && t < 64) {
        // lane t = batch t: poll the 8 tagged words it will consume
        u64 v[8];
        for (;;) {
            bool ready = true;
            #pragma unroll
            for (int k = 0; k < 8; ++k) {
                v[k] = __hip_atomic_load(&tagged[(t * 8 + k) * TAG_STRIDE],
                                         __ATOMIC_ACQUIRE,
                                         __HIP_MEMORY_SCOPE_AGENT);
                ready &= ((unsigned)(v[k] >> 32) == FLAG_PAT);
            }
            if (__all(ready)) break;
            __builtin_amdgcn_s_sleep(2);
        }
        // ordered sum of batch t's 8 partials (payload = low 32 bits)
        float ss = 0.0f;
        #pragma unroll
        for (int k = 0; k < 8; ++k)
            ss += __uint_as_float((unsigned)(v[k] & 0xFFFFFFFFull));
        // ss = 2 * sum_{i<j} (din-dtg)^2 for batch t
        float r = sqrtf(ss + 1e-6f) * (1.0f / (sqrtf(512.0f * 511.0f) * 512.0f));
        for (int o = 32; o > 0; o >>= 1) r += __shfl_down(r, o);
        if (t == 0) out[0] = r * (1.0f / (float)N_BATCH);
        // clear tags for the next stream-ordered call (kernel completion
        // publishes these before the next launch's loads)
        #pragma unroll
        for (int k = 0; k < 8; ++k)
            __hip_atomic_store(&tagged[(t * 8 + k) * TAG_STRIDE], 0ull,
                               __ATOMIC_RELAXED, __HIP_MEMORY_SCOPE_AGENT);
    }
}

extern "C" void kernel_launch(void* const* d_in, const int* in_sizes, int n_in,
                              void* d_out, int out_size, void* d_ws, size_t ws_size,
                              hipStream_t stream) {
    const float* inp = (const float*)d_in[0];   // [N,3,3] f32
    const float* tgt = (const float*)d_in[1];   // [N,3,3] f32
    u64*   tagged = (u64*)d_ws;                 // 512 x 64B-strided tagged words
    float* out    = (float*)d_out;

    rgn_fused_kernel<<<NBLOCKS, NTHR, 0, stream>>>(inp, tgt, tagged, out);
}

// Round 11
// 16.238 us; speedup vs baseline: 1.8221x; 1.0867x over previous
//
#include <hip/hip_runtime.h>
#include <math.h>

typedef float f32x2 __attribute__((ext_vector_type(2)));
typedef unsigned long long u64;

#define L_RES 512
#define N_BATCH 64
#define NTHR 512                          // 8 waves per block
#define BLK_PER_B 4                       // blocks per batch
#define NBLOCKS (N_BATCH * BLK_PER_B)     // 256 blocks = 1 per CU, 8 waves/CU
#define R_ROWS 8                          // rows held in registers per thread
#define JSTRIDE 32                        // 4 blocks x 8 waves = 32 phases -> 16 j-iters
#define FLAG_PAT 0xCCCCCCCCu              // != 0xAAAAAAAA poison, != 0
#define TAG_STRIDE 8                      // u64s -> 64 B between tagged words

// Identity: 2 * sum_{i<j} (din-dtg)^2  ==  sum over ALL ordered (i,j) of
//   [ sq_in + sq_tg - 2*sqrt(sq_in*sq_tg) ]   (diagonal contributes 0).
//
// R10 change (isolated): 256 blocks x 512 threads instead of 512 x 256.
// Invariants held: 2048 threads/batch, 128 pairs/thread, 32 j-phases,
// 8 waves/CU occupancy, XCD-local batches (blocks b, b+64, b+128, b+192 are
// all == b mod 8 -> same XCD; 32 blocks/XCD). Halves the dispatch ramp
// (256 CP packets) and the finalizer poll span (256 tagged words, 4/lane).
//
// Tagged-payload completion (from R9, any-initial-state sound): each block
// publishes (FLAG_PAT<<32)|f32_bits(partial) with one release store at a
// 64B-strided private address; block 0 polls with acquire loads (readiness
// and payload in the same word), sums in fixed order (bit-deterministic),
// writes out, clears tags. Writers never wait -> deadlock-free.

__global__ __launch_bounds__(NTHR) void rgn_fused_kernel(
    const float* __restrict__ inp, const float* __restrict__ tgt,
    u64* __restrict__ tagged,      // [NBLOCKS * TAG_STRIDE], logical id b*4+q
    float* __restrict__ out)
{
    __shared__ f32x2 sx[L_RES];     // (input.x, target.x) per residue
    __shared__ f32x2 sy[L_RES];
    __shared__ f32x2 sz[L_RES];
    __shared__ float wsum[NTHR / 64];

    const int bhw  = blockIdx.x;
    const int b    = bhw & 63;        // batch id (same XCD for all its blocks)
    const int q    = bhw >> 6;        // block-within-batch 0..3
    const int lid  = b * BLK_PER_B + q;  // logical block id
    const int t    = threadIdx.x;
    const int lane = t & 63;
    const int wv   = t >> 6;          // wave 0..7

    const float* __restrict__ binp = inp + (size_t)b * L_RES * 9;
    const float* __restrict__ btgt = tgt + (size_t)b * L_RES * 9;

    // stage CA atom (atom 1 -> floats 3..5 of each residue's 9); 1 residue/thread
    for (int l = t; l < L_RES; l += NTHR) {
        sx[l] = (f32x2){binp[l*9+3], btgt[l*9+3]};
        sy[l] = (f32x2){binp[l*9+4], btgt[l*9+4]};
        sz[l] = (f32x2){binp[l*9+5], btgt[l*9+5]};
    }
    __syncthreads();

    // 8 rows per thread, strided by 64: i = lane + 64*r
    f32x2 rx[R_ROWS], ry[R_ROWS], rz[R_ROWS];
    #pragma unroll
    for (int r = 0; r < R_ROWS; ++r) {
        const int i = lane + 64 * r;
        rx[r] = sx[i]; ry[r] = sy[i]; rz[r] = sz[i];
    }

    f32x2 asq = (f32x2){0.0f, 0.0f};   // sum of (sq_in, sq_tg)
    float acx = 0.0f;                   // sum of sqrt(sq_in*sq_tg)

    const int ph = q * 8 + wv;                     // 0..31
    for (int j = ph; j < L_RES; j += JSTRIDE) {    // 16 iterations
        const f32x2 jx = sx[j], jy = sy[j], jz = sz[j];  // wave-uniform broadcast
        #pragma unroll
        for (int r = 0; r < R_ROWS; ++r) {
            f32x2 dx = rx[r] - jx;
            f32x2 dy = ry[r] - jy;
            f32x2 dz = rz[r] - jz;
            f32x2 sq = __builtin_elementwise_fma(dz, dz,
                        __builtin_elementwise_fma(dy, dy, dx * dx));
            asq += sq;
            acx += __builtin_amdgcn_sqrtf(sq.x * sq.y);
        }
    }

    // per-thread combine, then block reduce (8 waves)
    float a = (asq.x + asq.y) - 2.0f * acx;
    for (int o = 32; o > 0; o >>= 1) a += __shfl_down(a, o);
    if (lane == 0) wsum[wv] = a;
    __syncthreads();

    if (t == 0) {
        float s = ((((((wsum[0] + wsum[1]) + wsum[2]) + wsum[3])
                      + wsum[4]) + wsum[5]) + wsum[6]) + wsum[7];
        u64 v = ((u64)FLAG_PAT << 32) | (u64)__float_as_uint(s);
        __hip_atomic_store(&tagged[lid * TAG_STRIDE], v, __ATOMIC_RELEASE,
                           __HIP_MEMORY_SCOPE_AGENT);
    }

    // hw block 0 (logical 0), wave 0: sole finalizer
    if (bhw == 0 && t < 64) {
        // lane t = batch t: poll the 4 tagged words it will consume
        u64 v[BLK_PER_B];
        for (;;) {
            bool ready = true;
            #pragma unroll
            for (int k = 0; k < BLK_PER_B; ++k) {
                v[k] = __hip_atomic_load(&tagged[(t * BLK_PER_B + k) * TAG_STRIDE],
                                         __ATOMIC_ACQUIRE,
                                         __HIP_MEMORY_SCOPE_AGENT);
                ready &= ((unsigned)(v[k] >> 32) == FLAG_PAT);
            }
            if (__all(ready)) break;
            __builtin_amdgcn_s_sleep(2);
        }
        // ordered sum of batch t's 4 partials (payload = low 32 bits)
        float ss = 0.0f;
        #pragma unroll
        for (int k = 0; k < BLK_PER_B; ++k)
            ss += __uint_as_float((unsigned)(v[k] & 0xFFFFFFFFull));
        // ss = 2 * sum_{i<j} (din-dtg)^2 for batch t
        float r = sqrtf(ss + 1e-6f) * (1.0f / (sqrtf(512.0f * 511.0f) * 512.0f));
        for (int o = 32; o > 0; o >>= 1) r += __shfl_down(r, o);
        if (t == 0) out[0] = r * (1.0f / (float)N_BATCH);
        // clear tags for the next stream-ordered call
        #pragma unroll
        for (int k = 0; k < BLK_PER_B; ++k)
            __hip_atomic_store(&tagged[(t * BLK_PER_B + k) * TAG_STRIDE], 0ull,
                               __ATOMIC_RELAXED, __HIP_MEMORY_SCOPE_AGENT);
    }
}

extern "C" void kernel_launch(void* const* d_in, const int* in_sizes, int n_in,
                              void* d_out, int out_size, void* d_ws, size_t ws_size,
                              hipStream_t stream) {
    const float* inp = (const float*)d_in[0];   // [N,3,3] f32
    const float* tgt = (const float*)d_in[1];   // [N,3,3] f32
    u64*   tagged = (u64*)d_ws;                 // 256 x 64B-strided tagged words
    float* out    = (float*)d_out;

    rgn_fused_kernel<<<NBLOCKS, NTHR, 0, stream>>>(inp, tgt, tagged, out);
}